// Round 1
// baseline (252.392 us; speedup 1.0000x reference)
//
#include <hip/hip_runtime.h>

#define NH 12

typedef __bf16 bf16x8 __attribute__((ext_vector_type(8)));
typedef float f32x4 __attribute__((ext_vector_type(4)));

typedef const __attribute__((address_space(1))) void* gas_ptr;
typedef __attribute__((address_space(3))) void* las_ptr;

__device__ __forceinline__ void gload_lds16(const __bf16* g, __bf16* l) {
    __builtin_amdgcn_global_load_lds((gas_ptr)g, (las_ptr)l, 16, 0, 0);
}

// ---------------- fp32 -> bf16 conversion of inputs ----------------
__global__ void convert_kernel(const float* __restrict__ hs,
                               const float* __restrict__ w1,
                               const float* __restrict__ w2,
                               __bf16* __restrict__ xh,
                               __bf16* __restrict__ wq,
                               __bf16* __restrict__ wo) {
    const long long N0 = 6291456;   // hidden 1024*8*768
    const long long N1 = 1769472;   // in_proj_weight 2304*768
    const long long N2 = 589824;    // out_proj_weight 768*768
    long long i = (long long)blockIdx.x * blockDim.x + threadIdx.x;
    long long stride = (long long)gridDim.x * blockDim.x;
    for (; i < N0 + N1 + N2; i += stride) {
        if (i < N0)            xh[i]            = (__bf16)hs[i];
        else if (i < N0 + N1)  wq[i - N0]       = (__bf16)w1[i - N0];
        else                   wo[i - N0 - N1]  = (__bf16)w2[i - N0 - N1];
    }
}

// ---------------- NT bf16 MFMA GEMM: C = A(MxK) * B(NxK)^T + bias ----------------
// MODE 0: epilogue routes to q (scaled, head-layout), k (head-layout), vT (d-major)
// MODE 1: epilogue writes fp32 to outf
template <int MODE>
__global__ __launch_bounds__(256) void gemm_nt(
    const __bf16* __restrict__ A, const __bf16* __restrict__ Bm,
    const float* __restrict__ bias,
    __bf16* __restrict__ qb, __bf16* __restrict__ kb, __bf16* __restrict__ vT,
    float* __restrict__ outf, int M, int N, int K)
{
    __shared__ __bf16 As[128 * 32];
    __shared__ __bf16 Bs[128 * 32];
    const int t = threadIdx.x;
    const int lane = t & 63;
    const int w = t >> 6;
    const int wr = w >> 1, wc = w & 1;
    const int m0 = blockIdx.y * 128, n0 = blockIdx.x * 128;
    const int fr = lane & 15, ko = (lane >> 4) * 8;

    f32x4 acc[4][4];
    const f32x4 z4 = {0.f, 0.f, 0.f, 0.f};
#pragma unroll
    for (int i = 0; i < 4; i++)
#pragma unroll
        for (int j = 0; j < 4; j++) acc[i][j] = z4;

    for (int kt = 0; kt < K; kt += 32) {
        // stage A tile (128x32) and B tile (128x32): linear LDS, 16B per lane
        gload_lds16(A + (size_t)(m0 + (t >> 2)) * K + kt + (t & 3) * 8, &As[t * 8]);
        gload_lds16(A + (size_t)(m0 + 64 + (t >> 2)) * K + kt + (t & 3) * 8, &As[2048 + t * 8]);
        gload_lds16(Bm + (size_t)(n0 + (t >> 2)) * K + kt + (t & 3) * 8, &Bs[t * 8]);
        gload_lds16(Bm + (size_t)(n0 + 64 + (t >> 2)) * K + kt + (t & 3) * 8, &Bs[2048 + t * 8]);
        __syncthreads();

        bf16x8 af[4], bfr[4];
#pragma unroll
        for (int i = 0; i < 4; i++) af[i] = *(const bf16x8*)&As[(wr * 64 + i * 16 + fr) * 32 + ko];
#pragma unroll
        for (int j = 0; j < 4; j++) bfr[j] = *(const bf16x8*)&Bs[(wc * 64 + j * 16 + fr) * 32 + ko];
#pragma unroll
        for (int i = 0; i < 4; i++)
#pragma unroll
            for (int j = 0; j < 4; j++)
                acc[i][j] = __builtin_amdgcn_mfma_f32_16x16x32_bf16(af[i], bfr[j], acc[i][j], 0, 0, 0);
        __syncthreads();
    }

#pragma unroll
    for (int i = 0; i < 4; i++)
#pragma unroll
        for (int j = 0; j < 4; j++)
#pragma unroll
            for (int r = 0; r < 4; r++) {
                int gr = m0 + wr * 64 + i * 16 + ((lane >> 4) << 2) + r;
                int gc = n0 + wc * 64 + j * 16 + (lane & 15);
                float val = acc[i][j][r] + bias[gc];
                if (MODE == 0) {
                    int s = gr >> 3, b = gr & 7;
                    int which = gc / 768;
                    int jj = gc - which * 768;
                    int head = jj >> 6, dim = jj & 63;
                    size_t n = (size_t)(b * NH + head);
                    if (which == 0)      qb[(n * 1024 + s) * 64 + dim] = (__bf16)(val * 0.125f);
                    else if (which == 1) kb[(n * 1024 + s) * 64 + dim] = (__bf16)val;
                    else                 vT[(n * 64 + dim) * 1024 + s] = (__bf16)val;
                } else {
                    outf[(size_t)gr * N + gc] = val;
                }
            }
}

// ---------------- flash attention: 1 block = 64 q-rows of one head ----------------
__global__ __launch_bounds__(256) void attn_kernel(
    const __bf16* __restrict__ qb, const __bf16* __restrict__ kb,
    const __bf16* __restrict__ vT, __bf16* __restrict__ ctx)
{
    __shared__ __bf16 Kl[32 * 64];     // [key][d]
    __shared__ __bf16 Vl[64 * 32];     // [d][key]  (from vT)
    __shared__ __bf16 Pl[4][16 * 32];  // per-wave P tile [qrow][key]
    const int t = threadIdx.x, lane = t & 63, w = t >> 6;
    const int n = blockIdx.y;          // head index 0..95 (= b*12 + head)
    const int q0 = blockIdx.x * 64;
    const int fr = lane & 15, g4 = lane >> 4;

    // Q fragments held in registers: rows q0 + w*16 + fr, d split in two halves
    const __bf16* qptr = qb + ((size_t)n * 1024 + q0 + w * 16 + fr) * 64 + g4 * 8;
    const bf16x8 qf0 = *(const bf16x8*)qptr;
    const bf16x8 qf1 = *(const bf16x8*)(qptr + 32);

    float mrow[4], lrow[4];
    const f32x4 z4 = {0.f, 0.f, 0.f, 0.f};
    f32x4 o[4] = {z4, z4, z4, z4};
#pragma unroll
    for (int r = 0; r < 4; r++) { mrow[r] = -1e30f; lrow[r] = 0.f; }

    for (int kc = 0; kc < 32; kc++) {
        const int t0 = kc * 32;
        gload_lds16(kb + ((size_t)n * 1024 + t0 + (t >> 3)) * 64 + (t & 7) * 8, &Kl[t * 8]);
        gload_lds16(vT + ((size_t)n * 64 + (t >> 2)) * 1024 + t0 + (t & 3) * 8, &Vl[t * 8]);
        __syncthreads();

        // QK^T for two 16-key tiles
        f32x4 sc[2];
#pragma unroll
        for (int tt = 0; tt < 2; tt++) {
            bf16x8 kf0 = *(const bf16x8*)&Kl[(tt * 16 + fr) * 64 + g4 * 8];
            bf16x8 kf1 = *(const bf16x8*)&Kl[(tt * 16 + fr) * 64 + 32 + g4 * 8];
            f32x4 s = z4;
            s = __builtin_amdgcn_mfma_f32_16x16x32_bf16(qf0, kf0, s, 0, 0, 0);
            s = __builtin_amdgcn_mfma_f32_16x16x32_bf16(qf1, kf1, s, 0, 0, 0);
            sc[tt] = s;
        }

        // online softmax per row (row = g4*4 + r), 16-lane group reduces
#pragma unroll
        for (int r = 0; r < 4; r++) {
            float v0 = sc[0][r], v1 = sc[1][r];
            float mx = fmaxf(v0, v1);
#pragma unroll
            for (int off = 1; off < 16; off <<= 1) mx = fmaxf(mx, __shfl_xor(mx, off));
            float mnew = fmaxf(mrow[r], mx);
            float scalef = __expf(mrow[r] - mnew);
            float p0 = __expf(v0 - mnew);
            float p1 = __expf(v1 - mnew);
            float ps = p0 + p1;
#pragma unroll
            for (int off = 1; off < 16; off <<= 1) ps += __shfl_xor(ps, off);
            lrow[r] = lrow[r] * scalef + ps;
            mrow[r] = mnew;
#pragma unroll
            for (int dt = 0; dt < 4; dt++) o[dt][r] *= scalef;
            int rl = g4 * 4 + r;
            Pl[w][rl * 32 + fr]      = (__bf16)p0;
            Pl[w][rl * 32 + 16 + fr] = (__bf16)p1;
        }
        __syncthreads();

        // PV: ctx(16x64) += P(16x32) * V(32x64)
        bf16x8 pa = *(const bf16x8*)&Pl[w][fr * 32 + g4 * 8];
#pragma unroll
        for (int dt = 0; dt < 4; dt++) {
            bf16x8 vf = *(const bf16x8*)&Vl[(dt * 16 + fr) * 32 + g4 * 8];
            o[dt] = __builtin_amdgcn_mfma_f32_16x16x32_bf16(pa, vf, o[dt], 0, 0, 0);
        }
        __syncthreads();
    }

    // write ctx in (S, B, H) layout as bf16 for the out-proj GEMM
    const int b = n / NH, head = n % NH;
#pragma unroll
    for (int dt = 0; dt < 4; dt++)
#pragma unroll
        for (int r = 0; r < 4; r++) {
            int srow = q0 + w * 16 + g4 * 4 + r;
            float val = o[dt][r] / lrow[r];
            ctx[((size_t)srow * 8 + b) * 768 + head * 64 + dt * 16 + fr] = (__bf16)val;
        }
}

extern "C" void kernel_launch(void* const* d_in, const int* in_sizes, int n_in,
                              void* d_out, int out_size, void* d_ws, size_t ws_size,
                              hipStream_t stream) {
    const float* hs = (const float*)d_in[0];
    const float* w1 = (const float*)d_in[1];
    const float* b1 = (const float*)d_in[2];
    const float* w2 = (const float*)d_in[3];
    const float* b2 = (const float*)d_in[4];
    float* out = (float*)d_out;

    char* ws = (char*)d_ws;
    __bf16* qb  = (__bf16*)(ws);                 // 96*1024*64 bf16 = 12.58 MB
    __bf16* kb  = (__bf16*)(ws + 12582912);      // 12.58 MB
    __bf16* vT  = (__bf16*)(ws + 25165824);      // 12.58 MB (d-major per head)
    __bf16* Xh  = (__bf16*)(ws + 37748736);      // 12.58 MB (hidden bf16)
    __bf16* Wq  = (__bf16*)(ws + 50331648);      // 3.54 MB
    __bf16* Wo  = (__bf16*)(ws + 53870592);      // 1.18 MB  (total ~55 MB)
    __bf16* Ctx = Xh;                            // Xh dead after GEMM1 -> reuse

    convert_kernel<<<2048, 256, 0, stream>>>(hs, w1, w2, Xh, Wq, Wo);
    gemm_nt<0><<<dim3(18, 64), 256, 0, stream>>>(Xh, Wq, b1, qb, kb, vT, nullptr, 8192, 2304, 768);
    attn_kernel<<<dim3(16, 96), 256, 0, stream>>>(qb, kb, vT, Ctx);
    gemm_nt<1><<<dim3(6, 64), 256, 0, stream>>>(Ctx, Wo, b2, nullptr, nullptr, nullptr, out, 8192, 768, 768);
}

// Round 2
// 205.041 us; speedup vs baseline: 1.2309x; 1.2309x over previous
//
#include <hip/hip_runtime.h>

#define NH 12

typedef __bf16 bf16x8 __attribute__((ext_vector_type(8)));
typedef float f32x4 __attribute__((ext_vector_type(4)));

typedef const __attribute__((address_space(1))) void* gas_ptr;
typedef __attribute__((address_space(3))) void* las_ptr;

__device__ __forceinline__ void gload_lds16(const __bf16* g, __bf16* l) {
    __builtin_amdgcn_global_load_lds((gas_ptr)g, (las_ptr)l, 16, 0, 0);
}

// ---------------- fp32 -> bf16 conversion of inputs ----------------
__global__ void convert_kernel(const float* __restrict__ hs,
                               const float* __restrict__ w1,
                               const float* __restrict__ w2,
                               __bf16* __restrict__ xh,
                               __bf16* __restrict__ wq,
                               __bf16* __restrict__ wo) {
    const long long N0 = 6291456;   // hidden 1024*8*768
    const long long N1 = 1769472;   // in_proj_weight 2304*768
    const long long N2 = 589824;    // out_proj_weight 768*768
    long long i = (long long)blockIdx.x * blockDim.x + threadIdx.x;
    long long stride = (long long)gridDim.x * blockDim.x;
    for (; i < N0 + N1 + N2; i += stride) {
        if (i < N0)            xh[i]            = (__bf16)hs[i];
        else if (i < N0 + N1)  wq[i - N0]       = (__bf16)w1[i - N0];
        else                   wo[i - N0 - N1]  = (__bf16)w2[i - N0 - N1];
    }
}

// ---------------- NT bf16 MFMA GEMM: C = A(MxK) * B(NxK)^T + bias ----------------
template <int MODE>
__global__ __launch_bounds__(256) void gemm_nt(
    const __bf16* __restrict__ A, const __bf16* __restrict__ Bm,
    const float* __restrict__ bias,
    __bf16* __restrict__ qb, __bf16* __restrict__ kb, __bf16* __restrict__ vT,
    float* __restrict__ outf, int M, int N, int K)
{
    __shared__ __bf16 As[128 * 32];
    __shared__ __bf16 Bs[128 * 32];
    const int t = threadIdx.x;
    const int lane = t & 63;
    const int w = t >> 6;
    const int wr = w >> 1, wc = w & 1;
    const int m0 = blockIdx.y * 128, n0 = blockIdx.x * 128;
    const int fr = lane & 15, ko = (lane >> 4) * 8;

    f32x4 acc[4][4];
    const f32x4 z4 = {0.f, 0.f, 0.f, 0.f};
#pragma unroll
    for (int i = 0; i < 4; i++)
#pragma unroll
        for (int j = 0; j < 4; j++) acc[i][j] = z4;

    for (int kt = 0; kt < K; kt += 32) {
        gload_lds16(A + (size_t)(m0 + (t >> 2)) * K + kt + (t & 3) * 8, &As[t * 8]);
        gload_lds16(A + (size_t)(m0 + 64 + (t >> 2)) * K + kt + (t & 3) * 8, &As[2048 + t * 8]);
        gload_lds16(Bm + (size_t)(n0 + (t >> 2)) * K + kt + (t & 3) * 8, &Bs[t * 8]);
        gload_lds16(Bm + (size_t)(n0 + 64 + (t >> 2)) * K + kt + (t & 3) * 8, &Bs[2048 + t * 8]);
        __syncthreads();

        bf16x8 af[4], bfr[4];
#pragma unroll
        for (int i = 0; i < 4; i++) af[i] = *(const bf16x8*)&As[(wr * 64 + i * 16 + fr) * 32 + ko];
#pragma unroll
        for (int j = 0; j < 4; j++) bfr[j] = *(const bf16x8*)&Bs[(wc * 64 + j * 16 + fr) * 32 + ko];
#pragma unroll
        for (int i = 0; i < 4; i++)
#pragma unroll
            for (int j = 0; j < 4; j++)
                acc[i][j] = __builtin_amdgcn_mfma_f32_16x16x32_bf16(af[i], bfr[j], acc[i][j], 0, 0, 0);
        __syncthreads();
    }

#pragma unroll
    for (int i = 0; i < 4; i++)
#pragma unroll
        for (int j = 0; j < 4; j++)
#pragma unroll
            for (int r = 0; r < 4; r++) {
                int gr = m0 + wr * 64 + i * 16 + ((lane >> 4) << 2) + r;
                int gc = n0 + wc * 64 + j * 16 + (lane & 15);
                float val = acc[i][j][r] + bias[gc];
                if (MODE == 0) {
                    int s = gr >> 3, b = gr & 7;
                    int which = gc / 768;
                    int jj = gc - which * 768;
                    int head = jj >> 6, dim = jj & 63;
                    size_t n = (size_t)(b * NH + head);
                    if (which == 0)      qb[(n * 1024 + s) * 64 + dim] = (__bf16)(val * 0.125f);
                    else if (which == 1) kb[(n * 1024 + s) * 64 + dim] = (__bf16)val;
                    else                 vT[(n * 64 + dim) * 1024 + s] = (__bf16)val;
                } else {
                    outf[(size_t)gr * N + gc] = val;
                }
            }
}

// ---------------- flash attention: 1 block = 64 q-rows of one head ----------------
// KVBLK=64, double-buffered K/V staging (1 barrier/chunk), XOR-swizzled LDS
// (linear gload_lds dest + pre-swizzled global source + swizzled reads),
// per-wave P buffer (no barrier around softmax/PV), XCD-aware block swizzle.
__global__ __launch_bounds__(256) void attn_kernel(
    const __bf16* __restrict__ qb, const __bf16* __restrict__ kb,
    const __bf16* __restrict__ vT, __bf16* __restrict__ ctx)
{
    __shared__ __bf16 Kl[2][64 * 64];  // [key][d], swizzled
    __shared__ __bf16 Vl[2][64 * 64];  // [d][key], swizzled
    __shared__ __bf16 Pl[4][16 * 64];  // per-wave [qrow][key], swizzled
    const int t = threadIdx.x, lane = t & 63, w = t >> 6;

    // bijective XCD swizzle: 1536 blocks, 8 XCDs -> each XCD owns 12 heads
    const int orig = blockIdx.x;
    const int swz = (orig & 7) * (gridDim.x >> 3) + (orig >> 3);
    const int n = swz >> 4;            // head 0..95
    const int q0 = (swz & 15) * 64;
    const int fr = lane & 15, g4 = lane >> 4;

    const __bf16* qptr = qb + ((size_t)n * 1024 + q0 + w * 16 + fr) * 64 + g4 * 8;
    const bf16x8 qf0 = *(const bf16x8*)qptr;
    const bf16x8 qf1 = *(const bf16x8*)(qptr + 32);

    float mrow[4], lrow[4];
    const f32x4 z4 = {0.f, 0.f, 0.f, 0.f};
    f32x4 o[4] = {z4, z4, z4, z4};
#pragma unroll
    for (int r = 0; r < 4; r++) { mrow[r] = -1e30f; lrow[r] = 0.f; }

    // staging: lane t -> LDS linear slot (row = t>>3, colblk' = t&7);
    // source colblk pre-swizzled so that swizzled layout lands linearly.
    const int srow = t >> 3;
    const int scb  = (t & 7) ^ (srow & 7);
    const __bf16* kbase = kb + (size_t)n * 65536;
    const __bf16* vbase = vT + (size_t)n * 65536;

    int cur = 0;
    {   // prologue: stage chunk 0
        gload_lds16(kbase + (size_t)(0 + srow) * 64 + scb * 8,        &Kl[0][t * 8]);
        gload_lds16(kbase + (size_t)(32 + srow) * 64 + scb * 8,       &Kl[0][2048 + t * 8]);
        gload_lds16(vbase + (size_t)srow * 1024 + 0 + scb * 8,        &Vl[0][t * 8]);
        gload_lds16(vbase + (size_t)(32 + srow) * 1024 + 0 + scb * 8, &Vl[0][2048 + t * 8]);
        __syncthreads();
    }

    for (int kc = 0; kc < 16; kc++) {
        if (kc < 15) {  // prefetch next chunk into other buffer
            const int t0 = (kc + 1) * 64;
            const int nb = cur ^ 1;
            gload_lds16(kbase + (size_t)(t0 + srow) * 64 + scb * 8,         &Kl[nb][t * 8]);
            gload_lds16(kbase + (size_t)(t0 + 32 + srow) * 64 + scb * 8,    &Kl[nb][2048 + t * 8]);
            gload_lds16(vbase + (size_t)srow * 1024 + t0 + scb * 8,         &Vl[nb][t * 8]);
            gload_lds16(vbase + (size_t)(32 + srow) * 1024 + t0 + scb * 8,  &Vl[nb][2048 + t * 8]);
        }

        // ---- QK^T: 4 tiles of 16 keys ----
        f32x4 sc[4];
#pragma unroll
        for (int tt = 0; tt < 4; tt++) {
            const int row = tt * 16 + fr;
            bf16x8 kf0 = *(const bf16x8*)&Kl[cur][row * 64 + ((g4 ^ (fr & 7)) * 8)];
            bf16x8 kf1 = *(const bf16x8*)&Kl[cur][row * 64 + (((4 + g4) ^ (fr & 7)) * 8)];
            f32x4 s = z4;
            s = __builtin_amdgcn_mfma_f32_16x16x32_bf16(qf0, kf0, s, 0, 0, 0);
            s = __builtin_amdgcn_mfma_f32_16x16x32_bf16(qf1, kf1, s, 0, 0, 0);
            sc[tt] = s;
        }

        // ---- online softmax: row = g4*4 + r, 16-lane reduce over keys ----
#pragma unroll
        for (int r = 0; r < 4; r++) {
            float v0 = sc[0][r], v1 = sc[1][r], v2 = sc[2][r], v3 = sc[3][r];
            float mx = fmaxf(fmaxf(v0, v1), fmaxf(v2, v3));
#pragma unroll
            for (int off = 1; off < 16; off <<= 1) mx = fmaxf(mx, __shfl_xor(mx, off));
            const float mnew = fmaxf(mrow[r], mx);
            const float sf = __expf(mrow[r] - mnew);
            const float p0 = __expf(v0 - mnew);
            const float p1 = __expf(v1 - mnew);
            const float p2 = __expf(v2 - mnew);
            const float p3 = __expf(v3 - mnew);
            float ps = (p0 + p1) + (p2 + p3);
#pragma unroll
            for (int off = 1; off < 16; off <<= 1) ps += __shfl_xor(ps, off);
            lrow[r] = lrow[r] * sf + ps;
            mrow[r] = mnew;
#pragma unroll
            for (int dt = 0; dt < 4; dt++) o[dt][r] *= sf;
            const int rl = g4 * 4 + r;
            const int rx = (rl & 7);
            const int cb0 = fr >> 3, ci = fr & 7;
            Pl[w][rl * 64 + (((0 + cb0) ^ rx) * 8) + ci] = (__bf16)p0;
            Pl[w][rl * 64 + (((2 + cb0) ^ rx) * 8) + ci] = (__bf16)p1;
            Pl[w][rl * 64 + (((4 + cb0) ^ rx) * 8) + ci] = (__bf16)p2;
            Pl[w][rl * 64 + (((6 + cb0) ^ rx) * 8) + ci] = (__bf16)p3;
        }

        // ---- PV: ctx(16x64) += P(16x64) * V(64x64) ----
#pragma unroll
        for (int ks = 0; ks < 2; ks++) {
            bf16x8 pa = *(const bf16x8*)&Pl[w][fr * 64 + (((ks * 4 + g4) ^ (fr & 7)) * 8)];
#pragma unroll
            for (int dt = 0; dt < 4; dt++) {
                const int row = dt * 16 + fr;
                bf16x8 vf = *(const bf16x8*)&Vl[cur][row * 64 + (((ks * 4 + g4) ^ (fr & 7)) * 8)];
                o[dt] = __builtin_amdgcn_mfma_f32_16x16x32_bf16(pa, vf, o[dt], 0, 0, 0);
            }
        }

        if (kc < 15) __syncthreads();  // drains vmcnt (stage) + fences buffers
        cur ^= 1;
    }

    // write ctx in (S, B, H) layout as bf16 for the out-proj GEMM
    const int b = n / NH, head = n % NH;
#pragma unroll
    for (int dt = 0; dt < 4; dt++)
#pragma unroll
        for (int r = 0; r < 4; r++) {
            int srw = q0 + w * 16 + g4 * 4 + r;
            float val = o[dt][r] / lrow[r];
            ctx[((size_t)srw * 8 + b) * 768 + head * 64 + dt * 16 + fr] = (__bf16)val;
        }
}

extern "C" void kernel_launch(void* const* d_in, const int* in_sizes, int n_in,
                              void* d_out, int out_size, void* d_ws, size_t ws_size,
                              hipStream_t stream) {
    const float* hs = (const float*)d_in[0];
    const float* w1 = (const float*)d_in[1];
    const float* b1 = (const float*)d_in[2];
    const float* w2 = (const float*)d_in[3];
    const float* b2 = (const float*)d_in[4];
    float* out = (float*)d_out;

    char* ws = (char*)d_ws;
    __bf16* qb  = (__bf16*)(ws);                 // 12.58 MB
    __bf16* kb  = (__bf16*)(ws + 12582912);      // 12.58 MB
    __bf16* vT  = (__bf16*)(ws + 25165824);      // 12.58 MB
    __bf16* Xh  = (__bf16*)(ws + 37748736);      // 12.58 MB
    __bf16* Wq  = (__bf16*)(ws + 50331648);      // 3.54 MB
    __bf16* Wo  = (__bf16*)(ws + 53870592);      // 1.18 MB
    __bf16* Ctx = Xh;                            // Xh dead after GEMM1 -> reuse

    convert_kernel<<<2048, 256, 0, stream>>>(hs, w1, w2, Xh, Wq, Wo);
    gemm_nt<0><<<dim3(18, 64), 256, 0, stream>>>(Xh, Wq, b1, qb, kb, vT, nullptr, 8192, 2304, 768);
    attn_kernel<<<1536, 256, 0, stream>>>(qb, kb, vT, Ctx);
    gemm_nt<1><<<dim3(6, 64), 256, 0, stream>>>(Ctx, Wo, b2, nullptr, nullptr, nullptr, out, 8192, 768, 768);
}

// Round 3
// 153.791 us; speedup vs baseline: 1.6411x; 1.3332x over previous
//
#include <hip/hip_runtime.h>

#define NH 12

typedef __bf16 bf16x8 __attribute__((ext_vector_type(8)));
typedef __bf16 bf16x4 __attribute__((ext_vector_type(4)));
typedef float f32x4 __attribute__((ext_vector_type(4)));

typedef const __attribute__((address_space(1))) void* gas_ptr;
typedef __attribute__((address_space(3))) void* las_ptr;

__device__ __forceinline__ void gload_lds16(const __bf16* g, __bf16* l) {
    __builtin_amdgcn_global_load_lds((gas_ptr)g, (las_ptr)l, 16, 0, 0);
}

// Q scale folded with log2(e): attention runs in exp2 domain.
#define QSCALE 0.18033688011112042f   // 0.125 * log2(e)

// ---------------- fp32 -> bf16 conversion of inputs ----------------
__global__ void convert_kernel(const float* __restrict__ hs,
                               const float* __restrict__ w1,
                               const float* __restrict__ w2,
                               __bf16* __restrict__ xh,
                               __bf16* __restrict__ wq,
                               __bf16* __restrict__ wo) {
    const long long N0 = 6291456;
    const long long N1 = 1769472;
    const long long N2 = 589824;
    long long i = (long long)blockIdx.x * blockDim.x + threadIdx.x;
    long long stride = (long long)gridDim.x * blockDim.x;
    for (; i < N0 + N1 + N2; i += stride) {
        if (i < N0)            xh[i]            = (__bf16)hs[i];
        else if (i < N0 + N1)  wq[i - N0]       = (__bf16)w1[i - N0];
        else                   wo[i - N0 - N1]  = (__bf16)w2[i - N0 - N1];
    }
}

// ---------------- NT bf16 MFMA GEMM: C = A(MxK) * B(NxK)^T + bias ----------------
template <int MODE>
__global__ __launch_bounds__(256) void gemm_nt(
    const __bf16* __restrict__ A, const __bf16* __restrict__ Bm,
    const float* __restrict__ bias,
    __bf16* __restrict__ qb, __bf16* __restrict__ kb, __bf16* __restrict__ vT,
    float* __restrict__ outf, int M, int N, int K)
{
    __shared__ __bf16 As[128 * 32];
    __shared__ __bf16 Bs[128 * 32];
    const int t = threadIdx.x;
    const int lane = t & 63;
    const int w = t >> 6;
    const int wr = w >> 1, wc = w & 1;
    const int m0 = blockIdx.y * 128, n0 = blockIdx.x * 128;
    const int fr = lane & 15, ko = (lane >> 4) * 8, g4 = lane >> 4;

    f32x4 acc[4][4];
    const f32x4 z4 = {0.f, 0.f, 0.f, 0.f};
#pragma unroll
    for (int i = 0; i < 4; i++)
#pragma unroll
        for (int j = 0; j < 4; j++) acc[i][j] = z4;

    for (int kt = 0; kt < K; kt += 32) {
        gload_lds16(A + (size_t)(m0 + (t >> 2)) * K + kt + (t & 3) * 8, &As[t * 8]);
        gload_lds16(A + (size_t)(m0 + 64 + (t >> 2)) * K + kt + (t & 3) * 8, &As[2048 + t * 8]);
        gload_lds16(Bm + (size_t)(n0 + (t >> 2)) * K + kt + (t & 3) * 8, &Bs[t * 8]);
        gload_lds16(Bm + (size_t)(n0 + 64 + (t >> 2)) * K + kt + (t & 3) * 8, &Bs[2048 + t * 8]);
        __syncthreads();

        bf16x8 af[4], bfr[4];
#pragma unroll
        for (int i = 0; i < 4; i++) af[i] = *(const bf16x8*)&As[(wr * 64 + i * 16 + fr) * 32 + ko];
#pragma unroll
        for (int j = 0; j < 4; j++) bfr[j] = *(const bf16x8*)&Bs[(wc * 64 + j * 16 + fr) * 32 + ko];
#pragma unroll
        for (int i = 0; i < 4; i++)
#pragma unroll
            for (int j = 0; j < 4; j++)
                acc[i][j] = __builtin_amdgcn_mfma_f32_16x16x32_bf16(af[i], bfr[j], acc[i][j], 0, 0, 0);
        __syncthreads();
    }

#pragma unroll
    for (int j = 0; j < 4; j++) {
        const int gc = n0 + wc * 64 + j * 16 + fr;
        const float bv = bias[gc];
        int which = 0, head = 0, dim = 0;
        if (MODE == 0) {
            which = gc / 768;
            const int jj = gc - which * 768;
            head = jj >> 6; dim = jj & 63;
        }
#pragma unroll
        for (int i = 0; i < 4; i++)
#pragma unroll
            for (int r = 0; r < 4; r++) {
                const int gr = m0 + wr * 64 + i * 16 + g4 * 4 + r;
                const float val = acc[i][j][r] + bv;
                if (MODE == 0) {
                    const int s = gr >> 3, b = gr & 7;
                    const size_t n = (size_t)(b * NH + head);
                    if (which == 0)      qb[(n * 1024 + s) * 64 + dim] = (__bf16)(val * QSCALE);
                    else if (which == 1) kb[(n * 1024 + s) * 64 + dim] = (__bf16)val;
                    else                 vT[(n * 64 + dim) * 1024 + s] = (__bf16)val;
                } else {
                    outf[(size_t)gr * N + gc] = val;
                }
            }
    }
}

// ---------------- flash attention ----------------
// 8 waves / 512 thr / 128 q-rows per block. Swapped-operand MFMAs:
//   QK^T = mfma(K, Q) -> lane owns ONE q-row (col=lane&15), 16 key-scores in regs
//   PV   = mfma(V, P) -> q back in col; m/l/rescale scalar per lane
// In-lane softmax trees + 2 shfl_xor; defer-max (THR=8, exp2 domain);
// P packed as bf16x4 ds_write_b64; XOR-swizzled LDS; double-buffered staging.
__global__ __launch_bounds__(512) void attn_kernel(
    const __bf16* __restrict__ qb, const __bf16* __restrict__ kb,
    const __bf16* __restrict__ vT, __bf16* __restrict__ ctx)
{
    __shared__ __bf16 Kl[2][64 * 64];
    __shared__ __bf16 Vl[2][64 * 64];
    __shared__ __bf16 Pl[8][16 * 64];
    const int t = threadIdx.x, lane = t & 63, w = t >> 6;

    // bijective XCD swizzle: 768 blocks -> 96/XCD -> 12 heads/XCD
    const int orig = blockIdx.x;
    const int swz = (orig & 7) * 96 + (orig >> 3);
    const int n = swz >> 3;              // head 0..95
    const int q0 = (swz & 7) * 128;
    const int fr = lane & 15, g4 = lane >> 4;
    const int fx = fr & 7;

    const __bf16* qptr = qb + ((size_t)n * 1024 + q0 + w * 16 + fr) * 64 + g4 * 8;
    const bf16x8 qf0 = *(const bf16x8*)qptr;
    const bf16x8 qf1 = *(const bf16x8*)(qptr + 32);

    float mval = -1e30f, lval = 0.f;
    const f32x4 z4 = {0.f, 0.f, 0.f, 0.f};
    f32x4 o[4] = {z4, z4, z4, z4};

    const int srow = t >> 3;                 // 0..63
    const int scb  = (t & 7) ^ (srow & 7);   // pre-swizzled source col-block
    const __bf16* kbase = kb + (size_t)n * 65536;
    const __bf16* vbase = vT + (size_t)n * 65536;

    gload_lds16(kbase + (size_t)srow * 64 + scb * 8,   &Kl[0][t * 8]);
    gload_lds16(vbase + (size_t)srow * 1024 + scb * 8, &Vl[0][t * 8]);
    __syncthreads();

    int cur = 0;
    for (int kc = 0; kc < 16; kc++) {
        if (kc < 15) {
            const int t0 = (kc + 1) * 64;
            gload_lds16(kbase + (size_t)(t0 + srow) * 64 + scb * 8,  &Kl[cur ^ 1][t * 8]);
            gload_lds16(vbase + (size_t)srow * 1024 + t0 + scb * 8,  &Vl[cur ^ 1][t * 8]);
        }

        // ---- QK^T (swapped): sc[tt][r] = score[key = 16tt+4g4+r][q = fr] ----
        f32x4 sc[4];
#pragma unroll
        for (int tt = 0; tt < 4; tt++) {
            const int row = (tt * 16 + fr) * 64;
            bf16x8 kf0 = *(const bf16x8*)&Kl[cur][row + ((g4 ^ fx) * 8)];
            bf16x8 kf1 = *(const bf16x8*)&Kl[cur][row + (((4 + g4) ^ fx) * 8)];
            f32x4 s = __builtin_amdgcn_mfma_f32_16x16x32_bf16(kf0, qf0, z4, 0, 0, 0);
            s = __builtin_amdgcn_mfma_f32_16x16x32_bf16(kf1, qf1, s, 0, 0, 0);
            sc[tt] = s;
        }

        // ---- in-lane softmax over 16 values + cross-g4 (2 shfl) ----
        float a[16];
#pragma unroll
        for (int tt = 0; tt < 4; tt++)
#pragma unroll
            for (int r = 0; r < 4; r++) a[tt * 4 + r] = sc[tt][r];

        float m8[8];
#pragma unroll
        for (int i = 0; i < 8; i++) m8[i] = fmaxf(a[i], a[i + 8]);
        float m4a = fmaxf(m8[0], m8[4]), m4b = fmaxf(m8[1], m8[5]);
        float m4c = fmaxf(m8[2], m8[6]), m4d = fmaxf(m8[3], m8[7]);
        float pmax = fmaxf(fmaxf(m4a, m4b), fmaxf(m4c, m4d));
        pmax = fmaxf(pmax, __shfl_xor(pmax, 16));
        pmax = fmaxf(pmax, __shfl_xor(pmax, 32));

        if (pmax > mval + 8.0f) {        // defer-max: rescale only on real growth
            const float sf = __builtin_amdgcn_exp2f(mval - pmax);
            lval *= sf;
#pragma unroll
            for (int dt = 0; dt < 4; dt++) o[dt] *= sf;
            mval = pmax;
        }

        float p[16];
#pragma unroll
        for (int i = 0; i < 16; i++) p[i] = __builtin_amdgcn_exp2f(a[i] - mval);
        float s8[8];
#pragma unroll
        for (int i = 0; i < 8; i++) s8[i] = p[i] + p[i + 8];
        float s4a = s8[0] + s8[4], s4b = s8[1] + s8[5];
        float s4c = s8[2] + s8[6], s4d = s8[3] + s8[7];
        float psum = (s4a + s4b) + (s4c + s4d);
        psum += __shfl_xor(psum, 16);
        psum += __shfl_xor(psum, 32);
        lval += psum;

        // ---- pack P (keys 4g4+16tt+0..3, row fr) as bf16x4, swizzled ----
#pragma unroll
        for (int tt = 0; tt < 4; tt++) {
            bf16x4 pk;
            pk[0] = (__bf16)p[tt * 4 + 0];
            pk[1] = (__bf16)p[tt * 4 + 1];
            pk[2] = (__bf16)p[tt * 4 + 2];
            pk[3] = (__bf16)p[tt * 4 + 3];
            const int blk = (2 * tt + (g4 >> 1)) ^ fx;
            *(bf16x4*)&Pl[w][fr * 64 + blk * 8 + (g4 & 1) * 4] = pk;
        }

        // ---- PV (swapped): o[dt][r] -> d = 16dt+4g4+r, q = fr ----
#pragma unroll
        for (int ks = 0; ks < 2; ks++) {
            bf16x8 pa = *(const bf16x8*)&Pl[w][fr * 64 + (((4 * ks + g4) ^ fx) * 8)];
#pragma unroll
            for (int dt = 0; dt < 4; dt++) {
                bf16x8 vf = *(const bf16x8*)&Vl[cur][(dt * 16 + fr) * 64 + (((4 * ks + g4) ^ fx) * 8)];
                o[dt] = __builtin_amdgcn_mfma_f32_16x16x32_bf16(vf, pa, o[dt], 0, 0, 0);
            }
        }

        if (kc < 15) __syncthreads();
        cur ^= 1;
    }

    // ---- epilogue: q-row = fr (scalar l), d = 16dt+4g4+r, packed stores ----
    const int b = n / NH, head = n % NH;
    const float rl = 1.0f / lval;
    const int srw = q0 + w * 16 + fr;
    __bf16* cbase = ctx + ((size_t)srw * 8 + b) * 768 + head * 64;
#pragma unroll
    for (int dt = 0; dt < 4; dt++) {
        bf16x4 ov;
#pragma unroll
        for (int r = 0; r < 4; r++) ov[r] = (__bf16)(o[dt][r] * rl);
        *(bf16x4*)&cbase[dt * 16 + g4 * 4] = ov;
    }
}

extern "C" void kernel_launch(void* const* d_in, const int* in_sizes, int n_in,
                              void* d_out, int out_size, void* d_ws, size_t ws_size,
                              hipStream_t stream) {
    const float* hs = (const float*)d_in[0];
    const float* w1 = (const float*)d_in[1];
    const float* b1 = (const float*)d_in[2];
    const float* w2 = (const float*)d_in[3];
    const float* b2 = (const float*)d_in[4];
    float* out = (float*)d_out;

    char* ws = (char*)d_ws;
    __bf16* qb  = (__bf16*)(ws);
    __bf16* kb  = (__bf16*)(ws + 12582912);
    __bf16* vT  = (__bf16*)(ws + 25165824);
    __bf16* Xh  = (__bf16*)(ws + 37748736);
    __bf16* Wq  = (__bf16*)(ws + 50331648);
    __bf16* Wo  = (__bf16*)(ws + 53870592);
    __bf16* Ctx = Xh;

    convert_kernel<<<2048, 256, 0, stream>>>(hs, w1, w2, Xh, Wq, Wo);
    gemm_nt<0><<<dim3(18, 64), 256, 0, stream>>>(Xh, Wq, b1, qb, kb, vT, nullptr, 8192, 2304, 768);
    attn_kernel<<<768, 512, 0, stream>>>(qb, kb, vT, Ctx);
    gemm_nt<1><<<dim3(6, 64), 256, 0, stream>>>(Ctx, Wo, b2, nullptr, nullptr, nullptr, out, 8192, 768, 768);
}

// Round 4
// 134.276 us; speedup vs baseline: 1.8797x; 1.1453x over previous
//
#include <hip/hip_runtime.h>

#define NH 12

typedef __bf16 bf16x8 __attribute__((ext_vector_type(8)));
typedef __bf16 bf16x4 __attribute__((ext_vector_type(4)));
typedef float f32x4 __attribute__((ext_vector_type(4)));

typedef const __attribute__((address_space(1))) void* gas_ptr;
typedef __attribute__((address_space(3))) void* las_ptr;

__device__ __forceinline__ void gload_lds16(const __bf16* g, __bf16* l) {
    __builtin_amdgcn_global_load_lds((gas_ptr)g, (las_ptr)l, 16, 0, 0);
}

// Q scale folded with log2(e): attention runs in exp2 domain.
#define QSCALE 0.18033688011112042f   // 0.125 * log2(e)

// ---------------- fp32 -> bf16 conversion (vectorized: 8 elems/thread/iter) ----------------
__global__ void convert_kernel(const float* __restrict__ hs,
                               const float* __restrict__ w1,
                               const float* __restrict__ w2,
                               __bf16* __restrict__ xh,
                               __bf16* __restrict__ wq,
                               __bf16* __restrict__ wo) {
    const long long C0 = 786432;   // 6291456/8
    const long long C1 = 221184;   // 1769472/8
    const long long C2 = 73728;    // 589824/8
    long long i = (long long)blockIdx.x * blockDim.x + threadIdx.x;
    const long long stride = (long long)gridDim.x * blockDim.x;
    for (; i < C0 + C1 + C2; i += stride) {
        const float* src; __bf16* dst; long long j;
        if (i < C0)           { src = hs; dst = xh; j = i; }
        else if (i < C0 + C1) { src = w1; dst = wq; j = i - C0; }
        else                  { src = w2; dst = wo; j = i - C0 - C1; }
        f32x4 v0 = *(const f32x4*)(src + j * 8);
        f32x4 v1 = *(const f32x4*)(src + j * 8 + 4);
        bf16x8 o;
#pragma unroll
        for (int r = 0; r < 4; r++) { o[r] = (__bf16)v0[r]; o[4 + r] = (__bf16)v1[r]; }
        *(bf16x8*)(dst + j * 8) = o;
    }
}

// ---------------- NT bf16 MFMA GEMM: C = A(MxK) * B(NxK)^T + bias ----------------
// BK=64, XOR-swizzled LDS (linear gload_lds dest + pre-swizzled source + swizzled
// ds_read_b128), double-buffered prefetch (1 barrier/K-step), XCD-aware 1-D grid.
template <int MODE>
__global__ __launch_bounds__(256) void gemm_nt(
    const __bf16* __restrict__ A, const __bf16* __restrict__ Bm,
    const float* __restrict__ bias,
    __bf16* __restrict__ qb, __bf16* __restrict__ kb, __bf16* __restrict__ vT,
    float* __restrict__ outf, int M, int N, int K, int NXB)
{
    __shared__ __bf16 As[2][128 * 64];
    __shared__ __bf16 Bs[2][128 * 64];
    const int t = threadIdx.x;
    const int lane = t & 63;
    const int w = t >> 6;
    const int wr = w >> 1, wc = w & 1;
    const int fr = lane & 15, g4 = lane >> 4;

    // bijective XCD swizzle (grid % 8 == 0): each XCD gets contiguous chunk
    const int cpx = gridDim.x >> 3;
    const int orig = blockIdx.x;
    const int swz = (orig & 7) * cpx + (orig >> 3);
    const int bx = swz % NXB, by = swz / NXB;
    const int m0 = by * 128, n0 = bx * 128;

    f32x4 acc[4][4];
    const f32x4 z4 = {0.f, 0.f, 0.f, 0.f};
#pragma unroll
    for (int i = 0; i < 4; i++)
#pragma unroll
        for (int j = 0; j < 4; j++) acc[i][j] = z4;

    const int kSteps = K >> 6;

    // prologue: stage K-step 0 (4 chunks of A + 4 of B per thread)
#pragma unroll
    for (int i = 0; i < 4; i++) {
        const int c = i * 256 + t;
        const int row = c >> 3;
        const int cb = ((c & 7) ^ (row & 7)) * 8;   // pre-swizzled source chunk
        gload_lds16(A  + (size_t)(m0 + row) * K + cb, &As[0][c * 8]);
        gload_lds16(Bm + (size_t)(n0 + row) * K + cb, &Bs[0][c * 8]);
    }
    __syncthreads();

    int cur = 0;
    for (int ks = 0; ks < kSteps; ks++) {
        if (ks < kSteps - 1) {
            const int kt = (ks + 1) << 6;
#pragma unroll
            for (int i = 0; i < 4; i++) {
                const int c = i * 256 + t;
                const int row = c >> 3;
                const int cb = ((c & 7) ^ (row & 7)) * 8;
                gload_lds16(A  + (size_t)(m0 + row) * K + kt + cb, &As[cur ^ 1][c * 8]);
                gload_lds16(Bm + (size_t)(n0 + row) * K + kt + cb, &Bs[cur ^ 1][c * 8]);
            }
        }

#pragma unroll
        for (int h = 0; h < 2; h++) {
            bf16x8 af[4], bfr[4];
#pragma unroll
            for (int i = 0; i < 4; i++) {
                const int r = wr * 64 + i * 16 + fr;
                af[i] = *(const bf16x8*)&As[cur][r * 64 + (((h * 4 + g4) ^ (r & 7)) * 8)];
            }
#pragma unroll
            for (int j = 0; j < 4; j++) {
                const int r = wc * 64 + j * 16 + fr;
                bfr[j] = *(const bf16x8*)&Bs[cur][r * 64 + (((h * 4 + g4) ^ (r & 7)) * 8)];
            }
            __builtin_amdgcn_s_setprio(1);
#pragma unroll
            for (int i = 0; i < 4; i++)
#pragma unroll
                for (int j = 0; j < 4; j++)
                    acc[i][j] = __builtin_amdgcn_mfma_f32_16x16x32_bf16(af[i], bfr[j], acc[i][j], 0, 0, 0);
            __builtin_amdgcn_s_setprio(0);
        }
        __syncthreads();
        cur ^= 1;
    }

#pragma unroll
    for (int j = 0; j < 4; j++) {
        const int gc = n0 + wc * 64 + j * 16 + fr;
        const float bv = bias[gc];
        int which = 0, head = 0, dim = 0;
        if (MODE == 0) {
            which = gc / 768;
            const int jj = gc - which * 768;
            head = jj >> 6; dim = jj & 63;
        }
#pragma unroll
        for (int i = 0; i < 4; i++)
#pragma unroll
            for (int r = 0; r < 4; r++) {
                const int gr = m0 + wr * 64 + i * 16 + g4 * 4 + r;
                const float val = acc[i][j][r] + bv;
                if (MODE == 0) {
                    const int s = gr >> 3, b = gr & 7;
                    const size_t n = (size_t)(b * NH + head);
                    if (which == 0)      qb[(n * 1024 + s) * 64 + dim] = (__bf16)(val * QSCALE);
                    else if (which == 1) kb[(n * 1024 + s) * 64 + dim] = (__bf16)val;
                    else                 vT[(n * 64 + dim) * 1024 + s] = (__bf16)val;
                } else {
                    outf[(size_t)gr * N + gc] = val;
                }
            }
    }
}

// ---------------- flash attention ----------------
__global__ __launch_bounds__(512) void attn_kernel(
    const __bf16* __restrict__ qb, const __bf16* __restrict__ kb,
    const __bf16* __restrict__ vT, __bf16* __restrict__ ctx)
{
    __shared__ __bf16 Kl[2][64 * 64];
    __shared__ __bf16 Vl[2][64 * 64];
    __shared__ __bf16 Pl[8][16 * 64];
    const int t = threadIdx.x, lane = t & 63, w = t >> 6;

    const int orig = blockIdx.x;
    const int swz = (orig & 7) * 96 + (orig >> 3);
    const int n = swz >> 3;
    const int q0 = (swz & 7) * 128;
    const int fr = lane & 15, g4 = lane >> 4;
    const int fx = fr & 7;

    const __bf16* qptr = qb + ((size_t)n * 1024 + q0 + w * 16 + fr) * 64 + g4 * 8;
    const bf16x8 qf0 = *(const bf16x8*)qptr;
    const bf16x8 qf1 = *(const bf16x8*)(qptr + 32);

    float mval = -1e30f, lval = 0.f;
    const f32x4 z4 = {0.f, 0.f, 0.f, 0.f};
    f32x4 o[4] = {z4, z4, z4, z4};

    const int srow = t >> 3;
    const int scb  = (t & 7) ^ (srow & 7);
    const __bf16* kbase = kb + (size_t)n * 65536;
    const __bf16* vbase = vT + (size_t)n * 65536;

    gload_lds16(kbase + (size_t)srow * 64 + scb * 8,   &Kl[0][t * 8]);
    gload_lds16(vbase + (size_t)srow * 1024 + scb * 8, &Vl[0][t * 8]);
    __syncthreads();

    int cur = 0;
    for (int kc = 0; kc < 16; kc++) {
        if (kc < 15) {
            const int t0 = (kc + 1) * 64;
            gload_lds16(kbase + (size_t)(t0 + srow) * 64 + scb * 8,  &Kl[cur ^ 1][t * 8]);
            gload_lds16(vbase + (size_t)srow * 1024 + t0 + scb * 8,  &Vl[cur ^ 1][t * 8]);
        }

        // ---- QK^T (swapped): sc[tt][r] = score[key = 16tt+4g4+r][q = fr] ----
        f32x4 sc[4];
        __builtin_amdgcn_s_setprio(1);
#pragma unroll
        for (int tt = 0; tt < 4; tt++) {
            const int row = (tt * 16 + fr) * 64;
            bf16x8 kf0 = *(const bf16x8*)&Kl[cur][row + ((g4 ^ fx) * 8)];
            bf16x8 kf1 = *(const bf16x8*)&Kl[cur][row + (((4 + g4) ^ fx) * 8)];
            f32x4 s = __builtin_amdgcn_mfma_f32_16x16x32_bf16(kf0, qf0, z4, 0, 0, 0);
            s = __builtin_amdgcn_mfma_f32_16x16x32_bf16(kf1, qf1, s, 0, 0, 0);
            sc[tt] = s;
        }
        __builtin_amdgcn_s_setprio(0);

        // ---- in-lane softmax over 16 values + cross-g4 (2 shfl) ----
        float a[16];
#pragma unroll
        for (int tt = 0; tt < 4; tt++)
#pragma unroll
            for (int r = 0; r < 4; r++) a[tt * 4 + r] = sc[tt][r];

        float m8[8];
#pragma unroll
        for (int i = 0; i < 8; i++) m8[i] = fmaxf(a[i], a[i + 8]);
        float m4a = fmaxf(m8[0], m8[4]), m4b = fmaxf(m8[1], m8[5]);
        float m4c = fmaxf(m8[2], m8[6]), m4d = fmaxf(m8[3], m8[7]);
        float pmax = fmaxf(fmaxf(m4a, m4b), fmaxf(m4c, m4d));
        pmax = fmaxf(pmax, __shfl_xor(pmax, 16));
        pmax = fmaxf(pmax, __shfl_xor(pmax, 32));

        if (pmax > mval + 8.0f) {
            const float sf = __builtin_amdgcn_exp2f(mval - pmax);
            lval *= sf;
#pragma unroll
            for (int dt = 0; dt < 4; dt++) o[dt] *= sf;
            mval = pmax;
        }

        float p[16];
#pragma unroll
        for (int i = 0; i < 16; i++) p[i] = __builtin_amdgcn_exp2f(a[i] - mval);
        float s8[8];
#pragma unroll
        for (int i = 0; i < 8; i++) s8[i] = p[i] + p[i + 8];
        float s4a = s8[0] + s8[4], s4b = s8[1] + s8[5];
        float s4c = s8[2] + s8[6], s4d = s8[3] + s8[7];
        float psum = (s4a + s4b) + (s4c + s4d);
        psum += __shfl_xor(psum, 16);
        psum += __shfl_xor(psum, 32);
        lval += psum;

#pragma unroll
        for (int tt = 0; tt < 4; tt++) {
            bf16x4 pk;
            pk[0] = (__bf16)p[tt * 4 + 0];
            pk[1] = (__bf16)p[tt * 4 + 1];
            pk[2] = (__bf16)p[tt * 4 + 2];
            pk[3] = (__bf16)p[tt * 4 + 3];
            const int blk = (2 * tt + (g4 >> 1)) ^ fx;
            *(bf16x4*)&Pl[w][fr * 64 + blk * 8 + (g4 & 1) * 4] = pk;
        }

        // ---- PV (swapped): o[dt][r] -> d = 16dt+4g4+r, q = fr ----
        __builtin_amdgcn_s_setprio(1);
#pragma unroll
        for (int ks = 0; ks < 2; ks++) {
            bf16x8 pa = *(const bf16x8*)&Pl[w][fr * 64 + (((4 * ks + g4) ^ fx) * 8)];
#pragma unroll
            for (int dt = 0; dt < 4; dt++) {
                bf16x8 vf = *(const bf16x8*)&Vl[cur][(dt * 16 + fr) * 64 + (((4 * ks + g4) ^ fx) * 8)];
                o[dt] = __builtin_amdgcn_mfma_f32_16x16x32_bf16(vf, pa, o[dt], 0, 0, 0);
            }
        }
        __builtin_amdgcn_s_setprio(0);

        if (kc < 15) __syncthreads();
        cur ^= 1;
    }

    const int b = n / NH, head = n % NH;
    const float rl = 1.0f / lval;
    const int srw = q0 + w * 16 + fr;
    __bf16* cbase = ctx + ((size_t)srw * 8 + b) * 768 + head * 64;
#pragma unroll
    for (int dt = 0; dt < 4; dt++) {
        bf16x4 ov;
#pragma unroll
        for (int r = 0; r < 4; r++) ov[r] = (__bf16)(o[dt][r] * rl);
        *(bf16x4*)&cbase[dt * 16 + g4 * 4] = ov;
    }
}

extern "C" void kernel_launch(void* const* d_in, const int* in_sizes, int n_in,
                              void* d_out, int out_size, void* d_ws, size_t ws_size,
                              hipStream_t stream) {
    const float* hs = (const float*)d_in[0];
    const float* w1 = (const float*)d_in[1];
    const float* b1 = (const float*)d_in[2];
    const float* w2 = (const float*)d_in[3];
    const float* b2 = (const float*)d_in[4];
    float* out = (float*)d_out;

    char* ws = (char*)d_ws;
    __bf16* qb  = (__bf16*)(ws);
    __bf16* kb  = (__bf16*)(ws + 12582912);
    __bf16* vT  = (__bf16*)(ws + 25165824);
    __bf16* Xh  = (__bf16*)(ws + 37748736);
    __bf16* Wq  = (__bf16*)(ws + 50331648);
    __bf16* Wo  = (__bf16*)(ws + 53870592);
    __bf16* Ctx = Xh;

    convert_kernel<<<2048, 256, 0, stream>>>(hs, w1, w2, Xh, Wq, Wo);
    gemm_nt<0><<<1152, 256, 0, stream>>>(Xh, Wq, b1, qb, kb, vT, nullptr, 8192, 2304, 768, 18);
    attn_kernel<<<768, 512, 0, stream>>>(qb, kb, vT, Ctx);
    gemm_nt<1><<<384, 256, 0, stream>>>(Ctx, Wo, b2, nullptr, nullptr, nullptr, out, 8192, 768, 768, 6);
}

// Round 5
// 128.566 us; speedup vs baseline: 1.9631x; 1.0444x over previous
//
#include <hip/hip_runtime.h>

#define NH 12

typedef __bf16 bf16x8 __attribute__((ext_vector_type(8)));
typedef __bf16 bf16x4 __attribute__((ext_vector_type(4)));
typedef float f32x4 __attribute__((ext_vector_type(4)));

typedef const __attribute__((address_space(1))) void* gas_ptr;
typedef __attribute__((address_space(3))) void* las_ptr;

__device__ __forceinline__ void gload_lds16(const __bf16* g, __bf16* l) {
    __builtin_amdgcn_global_load_lds((gas_ptr)g, (las_ptr)l, 16, 0, 0);
}

// Q scale folded with log2(e): attention runs in exp2 domain.
#define QSCALE 0.18033688011112042f   // 0.125 * log2(e)

// ---------------- fp32 -> bf16 conversion (vectorized: 8 elems/thread/iter) ----------------
__global__ void convert_kernel(const float* __restrict__ hs,
                               const float* __restrict__ w1,
                               const float* __restrict__ w2,
                               __bf16* __restrict__ xh,
                               __bf16* __restrict__ wq,
                               __bf16* __restrict__ wo) {
    const long long C0 = 786432;   // 6291456/8
    const long long C1 = 221184;   // 1769472/8
    const long long C2 = 73728;    // 589824/8
    long long i = (long long)blockIdx.x * blockDim.x + threadIdx.x;
    const long long stride = (long long)gridDim.x * blockDim.x;
    for (; i < C0 + C1 + C2; i += stride) {
        const float* src; __bf16* dst; long long j;
        if (i < C0)           { src = hs; dst = xh; j = i; }
        else if (i < C0 + C1) { src = w1; dst = wq; j = i - C0; }
        else                  { src = w2; dst = wo; j = i - C0 - C1; }
        f32x4 v0 = *(const f32x4*)(src + j * 8);
        f32x4 v1 = *(const f32x4*)(src + j * 8 + 4);
        bf16x8 o;
#pragma unroll
        for (int r = 0; r < 4; r++) { o[r] = (__bf16)v0[r]; o[4 + r] = (__bf16)v1[r]; }
        *(bf16x8*)(dst + j * 8) = o;
    }
}

// ---------------- NT bf16 MFMA GEMM: C = A(MxK) * B(NxK)^T + bias ----------------
// 512 threads / 8 waves (2x4) per 128x128 tile -> 16 waves/CU at 2 blocks/CU.
// BK=64, XOR-swizzled LDS, double-buffered prefetch (1 barrier/K-step),
// bijective XCD swizzle on flattened 1-D grid.
template <int MODE>
__global__ __launch_bounds__(512) void gemm_nt(
    const __bf16* __restrict__ A, const __bf16* __restrict__ Bm,
    const float* __restrict__ bias,
    __bf16* __restrict__ qb, __bf16* __restrict__ kb, __bf16* __restrict__ vT,
    float* __restrict__ outf, int M, int N, int K, int NXB)
{
    __shared__ __bf16 As[2][128 * 64];
    __shared__ __bf16 Bs[2][128 * 64];
    const int t = threadIdx.x;
    const int lane = t & 63;
    const int w = t >> 6;
    const int wr = w >> 2, wc = w & 3;     // 2 x 4 wave grid; wave tile 64 x 32
    const int fr = lane & 15, g4 = lane >> 4;

    const int cpx = gridDim.x >> 3;
    const int orig = blockIdx.x;
    const int swz = (orig & 7) * cpx + (orig >> 3);
    const int bx = swz % NXB, by = swz / NXB;
    const int m0 = by * 128, n0 = bx * 128;

    f32x4 acc[4][2];
    const f32x4 z4 = {0.f, 0.f, 0.f, 0.f};
#pragma unroll
    for (int i = 0; i < 4; i++)
#pragma unroll
        for (int j = 0; j < 2; j++) acc[i][j] = z4;

    const int kSteps = K >> 6;

    // prologue: stage K-step 0 (2 chunks of A + 2 of B per thread)
#pragma unroll
    for (int i = 0; i < 2; i++) {
        const int c = i * 512 + t;
        const int row = c >> 3;
        const int cb = ((c & 7) ^ (row & 7)) * 8;   // pre-swizzled source chunk
        gload_lds16(A  + (size_t)(m0 + row) * K + cb, &As[0][c * 8]);
        gload_lds16(Bm + (size_t)(n0 + row) * K + cb, &Bs[0][c * 8]);
    }
    __syncthreads();

    int cur = 0;
    for (int ks = 0; ks < kSteps; ks++) {
        if (ks < kSteps - 1) {
            const int kt = (ks + 1) << 6;
#pragma unroll
            for (int i = 0; i < 2; i++) {
                const int c = i * 512 + t;
                const int row = c >> 3;
                const int cb = ((c & 7) ^ (row & 7)) * 8;
                gload_lds16(A  + (size_t)(m0 + row) * K + kt + cb, &As[cur ^ 1][c * 8]);
                gload_lds16(Bm + (size_t)(n0 + row) * K + kt + cb, &Bs[cur ^ 1][c * 8]);
            }
        }

#pragma unroll
        for (int h = 0; h < 2; h++) {
            bf16x8 af[4], bfr[2];
#pragma unroll
            for (int i = 0; i < 4; i++) {
                const int r = wr * 64 + i * 16 + fr;
                af[i] = *(const bf16x8*)&As[cur][r * 64 + (((h * 4 + g4) ^ (r & 7)) * 8)];
            }
#pragma unroll
            for (int j = 0; j < 2; j++) {
                const int r = wc * 32 + j * 16 + fr;
                bfr[j] = *(const bf16x8*)&Bs[cur][r * 64 + (((h * 4 + g4) ^ (r & 7)) * 8)];
            }
            __builtin_amdgcn_s_setprio(1);
#pragma unroll
            for (int i = 0; i < 4; i++)
#pragma unroll
                for (int j = 0; j < 2; j++)
                    acc[i][j] = __builtin_amdgcn_mfma_f32_16x16x32_bf16(af[i], bfr[j], acc[i][j], 0, 0, 0);
            __builtin_amdgcn_s_setprio(0);
        }
        __syncthreads();
        cur ^= 1;
    }

#pragma unroll
    for (int j = 0; j < 2; j++) {
        const int gc = n0 + wc * 32 + j * 16 + fr;
        const float bv = bias[gc];
        int which = 0, head = 0, dim = 0;
        if (MODE == 0) {
            which = gc / 768;
            const int jj = gc - which * 768;
            head = jj >> 6; dim = jj & 63;
        }
#pragma unroll
        for (int i = 0; i < 4; i++)
#pragma unroll
            for (int r = 0; r < 4; r++) {
                const int gr = m0 + wr * 64 + i * 16 + g4 * 4 + r;
                const float val = acc[i][j][r] + bv;
                if (MODE == 0) {
                    const int s = gr >> 3, b = gr & 7;
                    const size_t n = (size_t)(b * NH + head);
                    if (which == 0)      qb[(n * 1024 + s) * 64 + dim] = (__bf16)(val * QSCALE);
                    else if (which == 1) kb[(n * 1024 + s) * 64 + dim] = (__bf16)val;
                    else                 vT[(n * 64 + dim) * 1024 + s] = (__bf16)val;
                } else {
                    outf[(size_t)gr * N + gc] = val;
                }
            }
    }
}

// ---------------- flash attention ----------------
__global__ __launch_bounds__(512) void attn_kernel(
    const __bf16* __restrict__ qb, const __bf16* __restrict__ kb,
    const __bf16* __restrict__ vT, __bf16* __restrict__ ctx)
{
    __shared__ __bf16 Kl[2][64 * 64];
    __shared__ __bf16 Vl[2][64 * 64];
    __shared__ __bf16 Pl[8][16 * 64];
    const int t = threadIdx.x, lane = t & 63, w = t >> 6;

    const int orig = blockIdx.x;
    const int swz = (orig & 7) * 96 + (orig >> 3);
    const int n = swz >> 3;
    const int q0 = (swz & 7) * 128;
    const int fr = lane & 15, g4 = lane >> 4;
    const int fx = fr & 7;

    const __bf16* qptr = qb + ((size_t)n * 1024 + q0 + w * 16 + fr) * 64 + g4 * 8;
    const bf16x8 qf0 = *(const bf16x8*)qptr;
    const bf16x8 qf1 = *(const bf16x8*)(qptr + 32);

    float mval = -1e30f, lval = 0.f;
    const f32x4 z4 = {0.f, 0.f, 0.f, 0.f};
    f32x4 o[4] = {z4, z4, z4, z4};

    const int srow = t >> 3;
    const int scb  = (t & 7) ^ (srow & 7);
    const __bf16* kbase = kb + (size_t)n * 65536;
    const __bf16* vbase = vT + (size_t)n * 65536;

    gload_lds16(kbase + (size_t)srow * 64 + scb * 8,   &Kl[0][t * 8]);
    gload_lds16(vbase + (size_t)srow * 1024 + scb * 8, &Vl[0][t * 8]);
    __syncthreads();

    int cur = 0;
    for (int kc = 0; kc < 16; kc++) {
        if (kc < 15) {
            const int t0 = (kc + 1) * 64;
            gload_lds16(kbase + (size_t)(t0 + srow) * 64 + scb * 8,  &Kl[cur ^ 1][t * 8]);
            gload_lds16(vbase + (size_t)srow * 1024 + t0 + scb * 8,  &Vl[cur ^ 1][t * 8]);
        }

        // ---- QK^T (swapped): sc[tt][r] = score[key = 16tt+4g4+r][q = fr] ----
        f32x4 sc[4];
        __builtin_amdgcn_s_setprio(1);
#pragma unroll
        for (int tt = 0; tt < 4; tt++) {
            const int row = (tt * 16 + fr) * 64;
            bf16x8 kf0 = *(const bf16x8*)&Kl[cur][row + ((g4 ^ fx) * 8)];
            bf16x8 kf1 = *(const bf16x8*)&Kl[cur][row + (((4 + g4) ^ fx) * 8)];
            f32x4 s = __builtin_amdgcn_mfma_f32_16x16x32_bf16(kf0, qf0, z4, 0, 0, 0);
            s = __builtin_amdgcn_mfma_f32_16x16x32_bf16(kf1, qf1, s, 0, 0, 0);
            sc[tt] = s;
        }
        __builtin_amdgcn_s_setprio(0);

        // ---- in-lane softmax over 16 values + cross-g4 (2 shfl) ----
        float a[16];
#pragma unroll
        for (int tt = 0; tt < 4; tt++)
#pragma unroll
            for (int r = 0; r < 4; r++) a[tt * 4 + r] = sc[tt][r];

        float m8[8];
#pragma unroll
        for (int i = 0; i < 8; i++) m8[i] = fmaxf(a[i], a[i + 8]);
        float m4a = fmaxf(m8[0], m8[4]), m4b = fmaxf(m8[1], m8[5]);
        float m4c = fmaxf(m8[2], m8[6]), m4d = fmaxf(m8[3], m8[7]);
        float pmax = fmaxf(fmaxf(m4a, m4b), fmaxf(m4c, m4d));
        pmax = fmaxf(pmax, __shfl_xor(pmax, 16));
        pmax = fmaxf(pmax, __shfl_xor(pmax, 32));

        if (pmax > mval + 8.0f) {
            const float sf = __builtin_amdgcn_exp2f(mval - pmax);
            lval *= sf;
#pragma unroll
            for (int dt = 0; dt < 4; dt++) o[dt] *= sf;
            mval = pmax;
        }

        float p[16];
#pragma unroll
        for (int i = 0; i < 16; i++) p[i] = __builtin_amdgcn_exp2f(a[i] - mval);
        float s8[8];
#pragma unroll
        for (int i = 0; i < 8; i++) s8[i] = p[i] + p[i + 8];
        float s4a = s8[0] + s8[4], s4b = s8[1] + s8[5];
        float s4c = s8[2] + s8[6], s4d = s8[3] + s8[7];
        float psum = (s4a + s4b) + (s4c + s4d);
        psum += __shfl_xor(psum, 16);
        psum += __shfl_xor(psum, 32);
        lval += psum;

#pragma unroll
        for (int tt = 0; tt < 4; tt++) {
            bf16x4 pk;
            pk[0] = (__bf16)p[tt * 4 + 0];
            pk[1] = (__bf16)p[tt * 4 + 1];
            pk[2] = (__bf16)p[tt * 4 + 2];
            pk[3] = (__bf16)p[tt * 4 + 3];
            const int blk = (2 * tt + (g4 >> 1)) ^ fx;
            *(bf16x4*)&Pl[w][fr * 64 + blk * 8 + (g4 & 1) * 4] = pk;
        }

        // ---- PV (swapped): o[dt][r] -> d = 16dt+4g4+r, q = fr ----
        __builtin_amdgcn_s_setprio(1);
#pragma unroll
        for (int ks = 0; ks < 2; ks++) {
            bf16x8 pa = *(const bf16x8*)&Pl[w][fr * 64 + (((4 * ks + g4) ^ fx) * 8)];
#pragma unroll
            for (int dt = 0; dt < 4; dt++) {
                bf16x8 vf = *(const bf16x8*)&Vl[cur][(dt * 16 + fr) * 64 + (((4 * ks + g4) ^ fx) * 8)];
                o[dt] = __builtin_amdgcn_mfma_f32_16x16x32_bf16(vf, pa, o[dt], 0, 0, 0);
            }
        }
        __builtin_amdgcn_s_setprio(0);

        if (kc < 15) __syncthreads();
        cur ^= 1;
    }

    const int b = n / NH, head = n % NH;
    const float rl = 1.0f / lval;
    const int srw = q0 + w * 16 + fr;
    __bf16* cbase = ctx + ((size_t)srw * 8 + b) * 768 + head * 64;
#pragma unroll
    for (int dt = 0; dt < 4; dt++) {
        bf16x4 ov;
#pragma unroll
        for (int r = 0; r < 4; r++) ov[r] = (__bf16)(o[dt][r] * rl);
        *(bf16x4*)&cbase[dt * 16 + g4 * 4] = ov;
    }
}

extern "C" void kernel_launch(void* const* d_in, const int* in_sizes, int n_in,
                              void* d_out, int out_size, void* d_ws, size_t ws_size,
                              hipStream_t stream) {
    const float* hs = (const float*)d_in[0];
    const float* w1 = (const float*)d_in[1];
    const float* b1 = (const float*)d_in[2];
    const float* w2 = (const float*)d_in[3];
    const float* b2 = (const float*)d_in[4];
    float* out = (float*)d_out;

    char* ws = (char*)d_ws;
    __bf16* qb  = (__bf16*)(ws);
    __bf16* kb  = (__bf16*)(ws + 12582912);
    __bf16* vT  = (__bf16*)(ws + 25165824);
    __bf16* Xh  = (__bf16*)(ws + 37748736);
    __bf16* Wq  = (__bf16*)(ws + 50331648);
    __bf16* Wo  = (__bf16*)(ws + 53870592);
    __bf16* Ctx = Xh;

    convert_kernel<<<2048, 256, 0, stream>>>(hs, w1, w2, Xh, Wq, Wo);
    gemm_nt<0><<<1152, 512, 0, stream>>>(Xh, Wq, b1, qb, kb, vT, nullptr, 8192, 2304, 768, 18);
    attn_kernel<<<768, 512, 0, stream>>>(qb, kb, vT, Ctx);
    gemm_nt<1><<<384, 512, 0, stream>>>(Ctx, Wo, b2, nullptr, nullptr, nullptr, out, 8192, 768, 768, 6);
}